// Round 1
// baseline (273.950 us; speedup 1.0000x reference)
//
#include <hip/hip_runtime.h>

#define BATCH 65536

typedef __attribute__((ext_vector_type(8))) short bf16x8;
typedef __attribute__((ext_vector_type(4))) float f32x4;

__device__ __forceinline__ unsigned short f2bf(float f) {
  unsigned int u = __float_as_uint(f);
  u += 0x7fffu + ((u >> 16) & 1u);   // RNE
  return (unsigned short)(u >> 16);
}

// tanh(o) * sigmoid(u) with 2 exp + 1 rcp
__device__ __forceinline__ float gru_act(float u, float o) {
  float a  = __expf(-u);
  float a2 = __expf(-2.0f * o);
  return (1.0f - a2) / ((1.0f + a) * (1.0f + a2));
}

// conv 3x3 SAME on 3x3 grid, unrolled tap value
__device__ __forceinline__ float conv_tap(const float* __restrict__ w, int co, int ci,
                                          int p, int q, int CINTOT) {
  int pi = p / 3, pj = p % 3, qi = q / 3, qj = q % 3;
  int di = qi - pi + 1, dj = qj - pj + 1;
  if ((unsigned)di < 3u && (unsigned)dj < 3u)
    return w[((co * CINTOT + ci) * 3 + di) * 3 + dj];
  return 0.0f;
}

// BT[g][n][k] bf16, n = co*9+p in [0,COUT*9), k = ci*9+q in [0,CINX*9)
__global__ void build_bt(const float* __restrict__ wu, const float* __restrict__ wo,
                         unsigned short* __restrict__ BT, int COUT, int CINX, int CINTOT) {
  int NG = COUT * 9, K = CINX * 9;
  int total = 2 * NG * K;
  int e = blockIdx.x * 256 + threadIdx.x;
  if (e >= total) return;
  int g = e / (NG * K);
  int rem = e - g * (NG * K);
  int n = rem / K, k = rem - n * K;
  BT[e] = f2bf(conv_tap(g ? wo : wu, n / 9, k / 9, n % 9, k % 9, CINTOT));
}

// A1[g][n][q] fp32: layer-1 unrolled weights (cin_x = 1), 2*288*9 elems
__global__ void build_a1(const float* __restrict__ wu, const float* __restrict__ wo,
                         float* __restrict__ A1) {
  int e = blockIdx.x * 256 + threadIdx.x;
  if (e >= 5184) return;
  int g = e / 2592;
  int rem = e - g * 2592;
  int n = rem / 9, k = rem - n * 9;
  A1[e] = conv_tap(g ? wo : wu, n / 9, 0, n % 9, k, 33);
}

// Layer 1: fp32 vector. Block = 288 threads (one per output col n), 64 rows/block.
__global__ __launch_bounds__(288) void layer1_k(
    const float* __restrict__ xin, const float* __restrict__ A1,
    const float* __restrict__ b1u, const float* __restrict__ b1o,
    float* __restrict__ x1) {
  __shared__ float xl[64 * 12];
  int tid = threadIdx.x;
  int r0 = blockIdx.x * 64;
  for (int c = tid; c < 576; c += 288)
    xl[(c / 9) * 12 + (c % 9)] = xin[(size_t)r0 * 9 + c];
  __syncthreads();
  int n = tid;
  float au[9], ao[9];
#pragma unroll
  for (int q = 0; q < 9; ++q) {
    au[q] = A1[n * 9 + q];
    ao[q] = A1[2592 + n * 9 + q];
  }
  float bU = b1u[n / 9], bO = b1o[n / 9];
  for (int r = 0; r < 64; ++r) {
    const float* xr = &xl[r * 12];
    float u = bU, o = bO;
#pragma unroll
    for (int q = 0; q < 9; ++q) {
      float xv = xr[q];
      u = fmaf(au[q], xv, u);
      o = fmaf(ao[q], xv, o);
    }
    x1[(size_t)(r0 + r) * 288 + n] = gru_act(u, o);
  }
}

// Fused dual-gate GEMM + GRU activation.
// Grid: (M/64, NGATE/(NW*NF*16)). Block: NW waves; each wave owns NF col-frags
// per gate over all 64 rows (4 m-frags). acc[m][gate][f].
template <int NW, int NF>
__global__ __launch_bounds__(NW * 64, 2) void gemm_act(
    const float* __restrict__ Xin, const unsigned short* __restrict__ BT,
    const float* __restrict__ bu, const float* __restrict__ bo,
    float* __restrict__ Xout, int K, int NGATE) {
  constexpr int NT = NW * 64;
  constexpr int NROWS = NW * NF * 16;  // cols per gate per block
  constexpr int BCH = 2 * NROWS * 4;   // 16B chunks of B per K-step
  __shared__ __align__(16) unsigned short Alds[64 * 32];
  __shared__ __align__(16) unsigned short Blds[2 * NROWS * 32];

  const int tid = threadIdx.x;
  const int lane = tid & 63;
  const int wid = tid >> 6;
  const int lrow = lane & 15;
  const int jc = lane >> 4;
  const int r0 = blockIdx.x * 64;
  const int n0 = blockIdx.y * NROWS;

  f32x4 acc[4][2][NF] = {};

  for (int k0 = 0; k0 < K; k0 += 32) {
    // stage A: 64 rows x 32 k, fp32 -> bf16, XOR-swizzled 16B chunks
#pragma unroll
    for (int c = tid; c < 256; c += NT) {
      int row = c >> 2, part = c & 3;
      const float* gp = Xin + (size_t)(r0 + row) * K + k0 + part * 8;
      float4 v0 = *(const float4*)gp;
      float4 v1 = *(const float4*)(gp + 4);
      bf16x8 h;
      h[0] = (short)f2bf(v0.x); h[1] = (short)f2bf(v0.y);
      h[2] = (short)f2bf(v0.z); h[3] = (short)f2bf(v0.w);
      h[4] = (short)f2bf(v1.x); h[5] = (short)f2bf(v1.y);
      h[6] = (short)f2bf(v1.z); h[7] = (short)f2bf(v1.w);
      int dst = row * 64 + ((part ^ ((row >> 1) & 3)) << 4);
      *(bf16x8*)((char*)Alds + dst) = h;
    }
    // stage B: [2][NROWS] rows x 32 k bf16, same swizzle
#pragma unroll
    for (int c = tid; c < BCH; c += NT) {
      int row = c >> 2, part = c & 3;
      int gg = row >= NROWS;
      int ng = gg ? (NGATE + n0 + row - NROWS) : (n0 + row);
      const unsigned short* gp = BT + (size_t)ng * K + k0 + part * 8;
      bf16x8 v = *(const bf16x8*)gp;
      int dst = row * 64 + ((part ^ ((row >> 1) & 3)) << 4);
      *(bf16x8*)((char*)Blds + dst) = v;
    }
    __syncthreads();

    bf16x8 af[4];
#pragma unroll
    for (int m = 0; m < 4; ++m) {
      int row = m * 16 + lrow;
      af[m] = *(const bf16x8*)((const char*)Alds + row * 64 + ((jc ^ ((row >> 1) & 3)) << 4));
    }
    bf16x8 bfr[2][NF];
#pragma unroll
    for (int g = 0; g < 2; ++g)
#pragma unroll
      for (int f = 0; f < NF; ++f) {
        int row = g * NROWS + (wid * NF + f) * 16 + lrow;
        bfr[g][f] = *(const bf16x8*)((const char*)Blds + row * 64 + ((jc ^ ((row >> 1) & 3)) << 4));
      }
#pragma unroll
    for (int m = 0; m < 4; ++m)
#pragma unroll
      for (int g = 0; g < 2; ++g)
#pragma unroll
        for (int f = 0; f < NF; ++f)
          acc[m][g][f] = __builtin_amdgcn_mfma_f32_16x16x32_bf16(
              af[m], bfr[g][f], acc[m][g][f], 0, 0, 0);
    __syncthreads();
  }

  // epilogue: C/D layout col = lane&15, row = (lane>>4)*4 + t
#pragma unroll
  for (int m = 0; m < 4; ++m)
#pragma unroll
    for (int f = 0; f < NF; ++f) {
      int n = n0 + (wid * NF + f) * 16 + lrow;
      float bU = bu[n / 9], bO = bo[n / 9];
      f32x4 u = acc[m][0][f], o = acc[m][1][f];
#pragma unroll
      for (int t = 0; t < 4; ++t) {
        int r = r0 + m * 16 + jc * 4 + t;
        Xout[(size_t)r * NGATE + n] = gru_act(u[t] + bU, o[t] + bO);
      }
    }
}

// Dense head: out[r][j] = x3[r][:144] . wd[j][:144] + bd[j]
__global__ __launch_bounds__(256) void dense_k(
    const float* __restrict__ x3, const float* __restrict__ wd,
    const float* __restrict__ bd, float* __restrict__ out) {
  __shared__ __align__(16) float wl[1296];
  __shared__ float bl[9];
  int tid = threadIdx.x;
  for (int c = tid; c < 1296; c += 256) wl[c] = wd[c];
  if (tid < 9) bl[tid] = bd[tid];
  __syncthreads();
  size_t r = (size_t)blockIdx.x * 256 + tid;
  const float4* xr = (const float4*)(x3 + r * 144);
  float s[9];
#pragma unroll
  for (int j = 0; j < 9; ++j) s[j] = bl[j];
  for (int kk = 0; kk < 36; ++kk) {
    float4 xv = xr[kk];
#pragma unroll
    for (int j = 0; j < 9; ++j) {
      const float4 wv = *(const float4*)&wl[j * 144 + kk * 4];
      s[j] = fmaf(xv.x, wv.x, s[j]);
      s[j] = fmaf(xv.y, wv.y, s[j]);
      s[j] = fmaf(xv.z, wv.z, s[j]);
      s[j] = fmaf(xv.w, wv.w, s[j]);
    }
  }
#pragma unroll
  for (int j = 0; j < 9; ++j) out[r * 9 + j] = s[j];
}

extern "C" void kernel_launch(void* const* d_in, const int* in_sizes, int n_in,
                              void* d_out, int out_size, void* d_ws, size_t ws_size,
                              hipStream_t stream) {
  const float* inputs = (const float*)d_in[0];
  const float* wd  = (const float*)d_in[1];
  const float* bd  = (const float*)d_in[2];
  const float* w1u = (const float*)d_in[3];
  const float* b1u = (const float*)d_in[4];
  const float* w1o = (const float*)d_in[7];
  const float* b1o = (const float*)d_in[8];
  const float* w2u = (const float*)d_in[9];
  const float* b2u = (const float*)d_in[10];
  const float* w2o = (const float*)d_in[13];
  const float* b2o = (const float*)d_in[14];
  const float* w3u = (const float*)d_in[15];
  const float* b3u = (const float*)d_in[16];
  const float* w3o = (const float*)d_in[19];
  const float* b3o = (const float*)d_in[20];

  float* out = (float*)d_out;                    // [B][9]
  float* x1 = out + (size_t)BATCH * 9;           // [B][288]
  float* x2 = x1 + (size_t)BATCH * 288;          // [B][576]
  float* x3 = x2 + (size_t)BATCH * 576;          // [B][144]

  unsigned short* BT2 = (unsigned short*)d_ws;   // [2][576][288] bf16
  unsigned short* BT3 = BT2 + 331776;            // [2][144][576] bf16
  float* A1 = (float*)((char*)d_ws + 995328);    // [2][288][9] fp32

  build_bt<<<1296, 256, 0, stream>>>(w2u, w2o, BT2, 64, 32, 96);
  build_bt<<<648, 256, 0, stream>>>(w3u, w3o, BT3, 16, 64, 80);
  build_a1<<<21, 256, 0, stream>>>(w1u, w1o, A1);

  layer1_k<<<BATCH / 64, 288, 0, stream>>>(inputs, A1, b1u, b1o, x1);
  gemm_act<4, 3><<<dim3(BATCH / 64, 3), 256, 0, stream>>>(x1, BT2, b2u, b2o, x2, 288, 576);
  gemm_act<3, 3><<<dim3(BATCH / 64, 1), 192, 0, stream>>>(x2, BT3, b3u, b3o, x3, 576, 144);
  dense_k<<<BATCH / 256, 256, 0, stream>>>(x3, wd, bd, out);
}

// Round 2
// 214.583 us; speedup vs baseline: 1.2767x; 1.2767x over previous
//
#include <hip/hip_runtime.h>

#define BATCH 65536

typedef __attribute__((ext_vector_type(8))) short bf16x8;
typedef __attribute__((ext_vector_type(4))) float f32x4;

__device__ __forceinline__ unsigned short f2bf(float f) {
  unsigned int u = __float_as_uint(f);
  u += 0x7fffu + ((u >> 16) & 1u);   // RNE
  return (unsigned short)(u >> 16);
}
__device__ __forceinline__ float bf2f(unsigned short h) {
  return __uint_as_float(((unsigned)h) << 16);
}

// tanh(o) * sigmoid(u) with 2 exp + 1 rcp
__device__ __forceinline__ float gru_act(float u, float o) {
  float a  = __expf(-u);
  float a2 = __expf(-2.0f * o);
  return (1.0f - a2) / ((1.0f + a) * (1.0f + a2));
}

// conv 3x3 SAME on 3x3 grid, unrolled tap value
__device__ __forceinline__ float conv_tap(const float* __restrict__ w, int co, int ci,
                                          int p, int q, int CINTOT) {
  int pi = p / 3, pj = p % 3, qi = q / 3, qj = q % 3;
  int di = qi - pi + 1, dj = qj - pj + 1;
  if ((unsigned)di < 3u && (unsigned)dj < 3u)
    return w[((co * CINTOT + ci) * 3 + di) * 3 + dj];
  return 0.0f;
}

// BT[g][n][k] bf16, n = co*9+p, k = ci*9+q
__global__ void build_bt(const float* __restrict__ wu, const float* __restrict__ wo,
                         unsigned short* __restrict__ BT, int COUT, int CINX, int CINTOT) {
  int NG = COUT * 9, K = CINX * 9;
  int total = 2 * NG * K;
  int e = blockIdx.x * 256 + threadIdx.x;
  if (e >= total) return;
  int g = e / (NG * K);
  int rem = e - g * (NG * K);
  int n = rem / K, k = rem - n * K;
  BT[e] = f2bf(conv_tap(g ? wo : wu, n / 9, k / 9, n % 9, k % 9, CINTOT));
}

// A1 transposed: [g][q][c], c = col n in [0,288), q = input tap in [0,9)
__global__ void build_a1(const float* __restrict__ wu, const float* __restrict__ wo,
                         float* __restrict__ A1) {
  int e = blockIdx.x * 256 + threadIdx.x;
  if (e >= 5184) return;
  int g = e / 2592;
  int rem = e - g * 2592;
  int q = rem / 288, c = rem - q * 288;
  A1[e] = conv_tap(g ? wo : wu, c / 9, 0, c % 9, q, 33);
}

// ---- Kernel A: L1 (fp32 vector) + L2 GEMM with x1 persistent in LDS ----
__global__ __launch_bounds__(256, 2) void fused12(
    const float* __restrict__ xin, const float* __restrict__ A1,
    const float* __restrict__ b1u, const float* __restrict__ b1o,
    const unsigned short* __restrict__ BT2,
    const float* __restrict__ b2u, const float* __restrict__ b2o,
    float* __restrict__ x1, float* __restrict__ x2) {
  __shared__ __align__(16) char x1l[64 * 640];        // [64 rows][40 chunks of 16B], chunk^(row&7)
  __shared__ __align__(16) unsigned short Bl[384 * 32];
  __shared__ float xl[64 * 12];

  const int tid = threadIdx.x;
  const int lane = tid & 63;
  const int lrow = lane & 15;
  const int jc = lane >> 4;
  const int wid = tid >> 6;
  const int r0 = blockIdx.x * 64;

  for (int c = tid; c < 576; c += 256) xl[(c / 9) * 12 + (c % 9)] = xin[(size_t)r0 * 9 + c];
  __syncthreads();

  // L1: lanes = cols (coalesced x1 writes + coalesced weight loads)
  {
    float au0[9], ao0[9], au1[9], ao1[9];
    const int c1 = tid, c2 = tid + 256;
    const bool has2 = (c2 < 288);
#pragma unroll
    for (int q = 0; q < 9; ++q) {
      au0[q] = A1[q * 288 + c1];
      ao0[q] = A1[2592 + q * 288 + c1];
      au1[q] = has2 ? A1[q * 288 + c2] : 0.0f;
      ao1[q] = has2 ? A1[2592 + q * 288 + c2] : 0.0f;
    }
    float bu0 = b1u[c1 / 9], bo0 = b1o[c1 / 9];
    float bu1 = has2 ? b1u[c2 / 9] : 0.0f;
    float bo1 = has2 ? b1o[c2 / 9] : 0.0f;
    for (int r = 0; r < 64; ++r) {
      float xr[9];
#pragma unroll
      for (int q = 0; q < 9; ++q) xr[q] = xl[r * 12 + q];
      float u0 = bu0, o0 = bo0, u1 = bu1, o1 = bo1;
#pragma unroll
      for (int q = 0; q < 9; ++q) {
        u0 = fmaf(au0[q], xr[q], u0);
        o0 = fmaf(ao0[q], xr[q], o0);
        u1 = fmaf(au1[q], xr[q], u1);
        o1 = fmaf(ao1[q], xr[q], o1);
      }
      float v0 = gru_act(u0, o0);
      x1[(size_t)(r0 + r) * 288 + c1] = v0;
      *(unsigned short*)(x1l + r * 640 + (((c1 >> 3) ^ (r & 7)) << 4) + (c1 & 7) * 2) = f2bf(v0);
      if (has2) {
        float v1 = gru_act(u1, o1);
        x1[(size_t)(r0 + r) * 288 + c2] = v1;
        *(unsigned short*)(x1l + r * 640 + (((c2 >> 3) ^ (r & 7)) << 4) + (c2 & 7) * 2) = f2bf(v1);
      }
    }
  }
  // (first in-loop __syncthreads orders x1l writes before af reads)

  // L2 GEMM: 3 sequential n-chunks of 192 cols/gate
  for (int nch = 0; nch < 3; ++nch) {
    const int n0 = nch * 192;
    f32x4 acc[4][2][3] = {};
    for (int kt = 0; kt < 9; ++kt) {
#pragma unroll
      for (int ci = 0; ci < 6; ++ci) {
        int c = ci * 256 + tid;              // 1536 chunks
        int row = c >> 2, part = c & 3;
        int ng = (row >= 192) ? (576 + n0 + row - 192) : (n0 + row);
        bf16x8 v = *(const bf16x8*)(BT2 + (size_t)ng * 288 + kt * 32 + part * 8);
        *(bf16x8*)((char*)Bl + row * 64 + ((part ^ ((row >> 1) & 3)) << 4)) = v;
      }
      __syncthreads();
      bf16x8 af[4];
#pragma unroll
      for (int m = 0; m < 4; ++m) {
        int row = m * 16 + lrow;
        int c8 = kt * 4 + jc;
        af[m] = *(const bf16x8*)(x1l + row * 640 + ((c8 ^ (row & 7)) << 4));
      }
      bf16x8 bfr[2][3];
#pragma unroll
      for (int g = 0; g < 2; ++g)
#pragma unroll
        for (int f = 0; f < 3; ++f) {
          int row = g * 192 + (wid * 3 + f) * 16 + lrow;
          bfr[g][f] = *(const bf16x8*)((const char*)Bl + row * 64 + ((jc ^ ((row >> 1) & 3)) << 4));
        }
#pragma unroll
      for (int m = 0; m < 4; ++m)
#pragma unroll
        for (int g = 0; g < 2; ++g)
#pragma unroll
          for (int f = 0; f < 3; ++f)
            acc[m][g][f] = __builtin_amdgcn_mfma_f32_16x16x32_bf16(
                af[m], bfr[g][f], acc[m][g][f], 0, 0, 0);
      __syncthreads();
    }
    // epilogue: C/D col = lane&15, row = (lane>>4)*4 + t
#pragma unroll
    for (int m = 0; m < 4; ++m)
#pragma unroll
      for (int f = 0; f < 3; ++f) {
        int n = n0 + (wid * 3 + f) * 16 + lrow;
        float bU = b2u[n / 9], bO = b2o[n / 9];
        f32x4 u = acc[m][0][f], o = acc[m][1][f];
#pragma unroll
        for (int t = 0; t < 4; ++t) {
          int r = r0 + m * 16 + jc * 4 + t;
          x2[(size_t)r * 576 + n] = gru_act(u[t] + bU, o[t] + bO);
        }
      }
  }
}

// ---- Kernel B: L3 GEMM + dense head ----
__global__ __launch_bounds__(192, 2) void fused3d(
    const float* __restrict__ x2, const unsigned short* __restrict__ BT3,
    const float* __restrict__ b3u, const float* __restrict__ b3o,
    const float* __restrict__ wd, const float* __restrict__ bd,
    float* __restrict__ x3, float* __restrict__ out) {
  __shared__ __align__(16) unsigned short Al[64 * 32];
  __shared__ __align__(16) unsigned short Bl[288 * 32];
  __shared__ unsigned short x3l[64 * 146];   // odd dword stride -> bank spread
  __shared__ float wl[1296];
  __shared__ float bl[9];

  const int tid = threadIdx.x;
  const int lane = tid & 63;
  const int lrow = lane & 15;
  const int jc = lane >> 4;
  const int wid = tid >> 6;
  const int r0 = blockIdx.x * 64;

  for (int c = tid; c < 1296; c += 192) wl[c] = wd[c];
  if (tid < 9) bl[tid] = bd[tid];

  f32x4 acc[4][2][3] = {};
  for (int kt = 0; kt < 18; ++kt) {
    // stage A: x2 fp32 -> bf16, 256 chunks
    for (int c = tid; c < 256; c += 192) {
      int row = c >> 2, part = c & 3;
      const float* gp = x2 + (size_t)(r0 + row) * 576 + kt * 32 + part * 8;
      float4 q0 = *(const float4*)gp;
      float4 q1 = *(const float4*)(gp + 4);
      bf16x8 h;
      h[0] = (short)f2bf(q0.x); h[1] = (short)f2bf(q0.y);
      h[2] = (short)f2bf(q0.z); h[3] = (short)f2bf(q0.w);
      h[4] = (short)f2bf(q1.x); h[5] = (short)f2bf(q1.y);
      h[6] = (short)f2bf(q1.z); h[7] = (short)f2bf(q1.w);
      *(bf16x8*)((char*)Al + row * 64 + ((part ^ ((row >> 1) & 3)) << 4)) = h;
    }
    // stage B: 1152 chunks
#pragma unroll
    for (int ci = 0; ci < 6; ++ci) {
      int c = ci * 192 + tid;
      int row = c >> 2, part = c & 3;
      bf16x8 v = *(const bf16x8*)(BT3 + (size_t)row * 576 + kt * 32 + part * 8);
      *(bf16x8*)((char*)Bl + row * 64 + ((part ^ ((row >> 1) & 3)) << 4)) = v;
    }
    __syncthreads();
    bf16x8 af[4];
#pragma unroll
    for (int m = 0; m < 4; ++m) {
      int row = m * 16 + lrow;
      af[m] = *(const bf16x8*)((const char*)Al + row * 64 + ((jc ^ ((row >> 1) & 3)) << 4));
    }
    bf16x8 bfr[2][3];
#pragma unroll
    for (int g = 0; g < 2; ++g)
#pragma unroll
      for (int f = 0; f < 3; ++f) {
        int row = g * 144 + (wid * 3 + f) * 16 + lrow;
        bfr[g][f] = *(const bf16x8*)((const char*)Bl + row * 64 + ((jc ^ ((row >> 1) & 3)) << 4));
      }
#pragma unroll
    for (int m = 0; m < 4; ++m)
#pragma unroll
      for (int g = 0; g < 2; ++g)
#pragma unroll
        for (int f = 0; f < 3; ++f)
          acc[m][g][f] = __builtin_amdgcn_mfma_f32_16x16x32_bf16(
              af[m], bfr[g][f], acc[m][g][f], 0, 0, 0);
    __syncthreads();
  }

  // epilogue: act -> x3 (global fp32) + x3l (LDS bf16)
#pragma unroll
  for (int m = 0; m < 4; ++m)
#pragma unroll
    for (int f = 0; f < 3; ++f) {
      int n = (wid * 3 + f) * 16 + lrow;
      float bU = b3u[n / 9], bO = b3o[n / 9];
      f32x4 u = acc[m][0][f], o = acc[m][1][f];
#pragma unroll
      for (int t = 0; t < 4; ++t) {
        int r = m * 16 + jc * 4 + t;
        float v = gru_act(u[t] + bU, o[t] + bO);
        x3[(size_t)(r0 + r) * 144 + n] = v;
        x3l[r * 146 + n] = f2bf(v);
      }
    }
  __syncthreads();

  // dense: lanes = rows, wave = 3 output cols
  {
    int drow = tid & 63;
    int jb = (tid >> 6) * 3;
    float s0 = bl[jb], s1 = bl[jb + 1], s2 = bl[jb + 2];
    for (int k = 0; k < 144; k += 2) {
      unsigned pr = *(const unsigned*)&x3l[drow * 146 + k];
      float v0 = bf2f((unsigned short)pr);
      float v1 = bf2f((unsigned short)(pr >> 16));
      s0 = fmaf(v0, wl[jb * 144 + k], s0);
      s0 = fmaf(v1, wl[jb * 144 + k + 1], s0);
      s1 = fmaf(v0, wl[(jb + 1) * 144 + k], s1);
      s1 = fmaf(v1, wl[(jb + 1) * 144 + k + 1], s1);
      s2 = fmaf(v0, wl[(jb + 2) * 144 + k], s2);
      s2 = fmaf(v1, wl[(jb + 2) * 144 + k + 1], s2);
    }
    size_t ob = (size_t)(r0 + drow) * 9 + jb;
    out[ob] = s0; out[ob + 1] = s1; out[ob + 2] = s2;
  }
}

extern "C" void kernel_launch(void* const* d_in, const int* in_sizes, int n_in,
                              void* d_out, int out_size, void* d_ws, size_t ws_size,
                              hipStream_t stream) {
  const float* inputs = (const float*)d_in[0];
  const float* wd  = (const float*)d_in[1];
  const float* bd  = (const float*)d_in[2];
  const float* w1u = (const float*)d_in[3];
  const float* b1u = (const float*)d_in[4];
  const float* w1o = (const float*)d_in[7];
  const float* b1o = (const float*)d_in[8];
  const float* w2u = (const float*)d_in[9];
  const float* b2u = (const float*)d_in[10];
  const float* w2o = (const float*)d_in[13];
  const float* b2o = (const float*)d_in[14];
  const float* w3u = (const float*)d_in[15];
  const float* b3u = (const float*)d_in[16];
  const float* w3o = (const float*)d_in[19];
  const float* b3o = (const float*)d_in[20];

  float* out = (float*)d_out;                    // [B][9]
  float* x1 = out + (size_t)BATCH * 9;           // [B][288]
  float* x2 = x1 + (size_t)BATCH * 288;          // [B][576]
  float* x3 = x2 + (size_t)BATCH * 576;          // [B][144]

  unsigned short* BT2 = (unsigned short*)d_ws;   // [2][576][288] bf16
  unsigned short* BT3 = BT2 + 331776;            // [2][144][576] bf16
  float* A1 = (float*)((char*)d_ws + 995328);    // [2][9][288] fp32

  build_bt<<<1296, 256, 0, stream>>>(w2u, w2o, BT2, 64, 32, 96);
  build_bt<<<648, 256, 0, stream>>>(w3u, w3o, BT3, 16, 64, 80);
  build_a1<<<21, 256, 0, stream>>>(w1u, w1o, A1);

  fused12<<<BATCH / 64, 256, 0, stream>>>(inputs, A1, b1u, b1o, BT2, b2u, b2o, x1, x2);
  fused3d<<<BATCH / 64, 192, 0, stream>>>(x2, BT3, b3u, b3o, wd, bd, x3, out);
}